// Round 4
// baseline (188.975 us; speedup 1.0000x reference)
//
#include <hip/hip_runtime.h>

// B=64, L=512, D=768, V=100
// summed[b,l,:] = w0 * pooler[b,l,:] + w1 * xt[b,:]
//   xt[b,d] = e0*W[0,d] + e1*W[1,d] + b_dense[d],  (e0,e1) = emb_table[ids[b]]
//   s00 = t0.t0, s01 = t0.t1, s11 = t1.t1
//   row0 softmax over (s00,s01), row1 softmax over (s01,s11); w = column sums
// LayerNorm closed form from (S0,S1,s00,s01,s11).
//
// R1: 4 waves/block (occupancy) — turned out ~neutral: bottleneck wasn't waves.
// R3 post-mortem: per-row VMEM traffic was 18 KB (pooler 3 KB + params 15 KB
// re-read from L1/L2 every row) — the vector-return path was the saturated
// pipe, which is why occupancy didn't help.
// R4: each wave owns 8 consecutive rows; params hoisted to registers ONCE per
// wave (xt folds W0/W1/b into one vector; s11,S1 computed once — they don't
// depend on the row). Row loop touches only pooler (NT load, 1-row prefetch)
// and out (NT store): 3 KB read + 3 KB write per row.

constexpr int Bc = 64;
constexpr int Lc = 512;
constexpr int Dc = 768;            // = 192 float4 = 3 float4 per lane (wave64)
constexpr float LN_EPS = 1e-6f;
constexpr int WAVES_PER_BLOCK = 4;
constexpr int ROWS_PER_WAVE = 8;   // 32 rows/block; 512%32==0 so no batch split

typedef float nv_float4 __attribute__((ext_vector_type(4)));

__global__ __launch_bounds__(64 * WAVES_PER_BLOCK) void hier_attn_ln_kernel(
    const int*   __restrict__ ids,        // (B,1)
    const float* __restrict__ pooler,     // (B,L,D)
    const float* __restrict__ emb_table,  // (V,2)
    const float* __restrict__ W,          // (2,D)
    const float* __restrict__ bvec,       // (D,)
    const float* __restrict__ gamma,      // (D,)
    const float* __restrict__ beta,       // (D,)
    float*       __restrict__ out)        // (B,L,D)
{
    const int wave = threadIdx.x >> 6;
    const int lane = threadIdx.x & 63;
    const int row0 = (blockIdx.x * WAVES_PER_BLOCK + wave) * ROWS_PER_WAVE;
    const int b    = row0 >> 9;                             // L = 512

    const int id = ids[b];
    const float e0 = emb_table[id * 2 + 0];
    const float e1 = emb_table[id * 2 + 1];

    // ---- per-wave constants: xt, gamma, beta in registers; s11,S1 scalars ----
    float4 xt[3], gm[3], bt[3];
    float s11 = 0.f, S1 = 0.f;
#pragma unroll
    for (int j = 0; j < 3; ++j) {
        const int idx4 = lane + j * 64;
        float4 w0 = ((const float4*)W)[idx4];
        float4 w1 = ((const float4*)(W + Dc))[idx4];
        float4 bd = ((const float4*)bvec)[idx4];
        float4 x;
        x.x = fmaf(e0, w0.x, fmaf(e1, w1.x, bd.x));
        x.y = fmaf(e0, w0.y, fmaf(e1, w1.y, bd.y));
        x.z = fmaf(e0, w0.z, fmaf(e1, w1.z, bd.z));
        x.w = fmaf(e0, w0.w, fmaf(e1, w1.w, bd.w));
        xt[j] = x;
        gm[j] = ((const float4*)gamma)[idx4];
        bt[j] = ((const float4*)beta)[idx4];
        s11 += x.x*x.x + x.y*x.y + x.z*x.z + x.w*x.w;
        S1  += x.x + x.y + x.z + x.w;
    }
#pragma unroll
    for (int off = 32; off > 0; off >>= 1) {
        s11 += __shfl_xor(s11, off);
        S1  += __shfl_xor(S1,  off);
    }

    const nv_float4* prow4 = (const nv_float4*)(pooler + (size_t)row0 * Dc);
    nv_float4*       orow4 = (nv_float4*)(out + (size_t)row0 * Dc);
    const float invD = 1.f / (float)Dc;

    // ---- row loop: 3 KB NT read + 3 KB NT write per row, 1-row prefetch ----
    float4 pn[3];
#pragma unroll
    for (int j = 0; j < 3; ++j) {
        nv_float4 t = __builtin_nontemporal_load(&prow4[lane + j * 64]);
        pn[j] = make_float4(t.x, t.y, t.z, t.w);
    }

    for (int r = 0; r < ROWS_PER_WAVE; ++r) {
        float4 p[3];
#pragma unroll
        for (int j = 0; j < 3; ++j) p[j] = pn[j];
        if (r + 1 < ROWS_PER_WAVE) {
#pragma unroll
            for (int j = 0; j < 3; ++j) {
                nv_float4 t = __builtin_nontemporal_load(
                    &prow4[(size_t)(r + 1) * 192 + lane + j * 64]);
                pn[j] = make_float4(t.x, t.y, t.z, t.w);
            }
        }

        float s00 = 0.f, s01 = 0.f, S0 = 0.f;
#pragma unroll
        for (int j = 0; j < 3; ++j) {
            s00 += p[j].x*p[j].x  + p[j].y*p[j].y  + p[j].z*p[j].z  + p[j].w*p[j].w;
            s01 += p[j].x*xt[j].x + p[j].y*xt[j].y + p[j].z*xt[j].z + p[j].w*xt[j].w;
            S0  += p[j].x + p[j].y + p[j].z + p[j].w;
        }
#pragma unroll
        for (int off = 32; off > 0; off >>= 1) {
            s00 += __shfl_xor(s00, off);
            s01 += __shfl_xor(s01, off);
            S0  += __shfl_xor(S0,  off);
        }

        // Two 2-way softmaxes (max-subtracted: scores ~ O(768), exp overflows).
        const float m0  = fmaxf(s00, s01);
        const float a00 = __expf(s00 - m0);
        const float a01 = __expf(s01 - m0);
        const float r0  = 1.f / (a00 + a01);
        const float m1  = fmaxf(s01, s11);
        const float a10 = __expf(s01 - m1);
        const float a11 = __expf(s11 - m1);
        const float r1  = 1.f / (a10 + a11);
        const float w0s = a00 * r0 + a10 * r1;   // weight on pooler row
        const float w1s = a01 * r0 + a11 * r1;   // weight on xt

        const float mean = (w0s * S0 + w1s * S1) * invD;
        const float ex2  = (w0s*w0s*s00 + 2.f*w0s*w1s*s01 + w1s*w1s*s11) * invD;
        const float var  = ex2 - mean * mean;
        const float rstd = rsqrtf(var + LN_EPS);

#pragma unroll
        for (int j = 0; j < 3; ++j) {
            nv_float4 o;
            o.x = (fmaf(w0s, p[j].x, w1s * xt[j].x) - mean) * rstd * gm[j].x + bt[j].x;
            o.y = (fmaf(w0s, p[j].y, w1s * xt[j].y) - mean) * rstd * gm[j].y + bt[j].y;
            o.z = (fmaf(w0s, p[j].z, w1s * xt[j].z) - mean) * rstd * gm[j].z + bt[j].z;
            o.w = (fmaf(w0s, p[j].w, w1s * xt[j].w) - mean) * rstd * gm[j].w + bt[j].w;
            __builtin_nontemporal_store(o, &orow4[(size_t)r * 192 + lane + j * 64]);
        }
    }
}

extern "C" void kernel_launch(void* const* d_in, const int* in_sizes, int n_in,
                              void* d_out, int out_size, void* d_ws, size_t ws_size,
                              hipStream_t stream) {
    const int*   ids       = (const int*)  d_in[0];
    const float* pooler    = (const float*)d_in[1];
    const float* emb_table = (const float*)d_in[2];
    const float* W_dense   = (const float*)d_in[3];
    const float* b_dense   = (const float*)d_in[4];
    const float* gamma     = (const float*)d_in[5];
    const float* beta      = (const float*)d_in[6];
    float* out = (float*)d_out;

    const int nrows  = Bc * Lc;  // 32768
    const int blocks = nrows / (WAVES_PER_BLOCK * ROWS_PER_WAVE);  // 1024
    hipLaunchKernelGGL(hier_attn_ln_kernel,
                       dim3(blocks), dim3(64 * WAVES_PER_BLOCK),
                       0, stream,
                       ids, pooler, emb_table, W_dense, b_dense, gamma, beta, out);
}